// Round 1
// baseline (1943.935 us; speedup 1.0000x reference)
//
#include <hip/hip_runtime.h>

typedef unsigned int u32;
typedef unsigned short u16;

typedef short short8 __attribute__((ext_vector_type(8)));
typedef float f32x4 __attribute__((ext_vector_type(4)));

// ---------------- numeric helpers ----------------

__device__ __forceinline__ float fast_exp2(float x) {
#if __has_builtin(__builtin_amdgcn_exp2f)
  return __builtin_amdgcn_exp2f(x);
#else
  return exp2f(x);
#endif
}
__device__ __forceinline__ float fast_rcp(float x) {
#if __has_builtin(__builtin_amdgcn_rcpf)
  return __builtin_amdgcn_rcpf(x);
#else
  return 1.0f / x;
#endif
}
__device__ __forceinline__ float sigmf_(float x) {
  return fast_rcp(1.0f + fast_exp2(-1.44269504088896f * x));
}
__device__ __forceinline__ float tanhf_(float x) {
  float e = fast_exp2(2.88539008177793f * x);  // exp(2x)
  return 1.0f - 2.0f * fast_rcp(e + 1.0f);
}
__device__ __forceinline__ u16 f2bf(float x) {
  u32 u = __float_as_uint(x);
  u32 r = (u + 0x7fffu + ((u >> 16) & 1u)) >> 16;
  return (u16)r;
}

#if __has_builtin(__builtin_amdgcn_fdot2_f32_bf16)
typedef __bf16 bf16x2_t __attribute__((ext_vector_type(2)));
__device__ __forceinline__ float dot2bf(u32 w, u32 h, float acc) {
  return __builtin_amdgcn_fdot2_f32_bf16(__builtin_bit_cast(bf16x2_t, w),
                                         __builtin_bit_cast(bf16x2_t, h), acc, false);
}
#else
__device__ __forceinline__ float dot2bf(u32 w, u32 h, float acc) {
  float wl = __uint_as_float(w << 16);
  float wh = __uint_as_float(w & 0xffff0000u);
  float hl = __uint_as_float(h << 16);
  float hh = __uint_as_float(h & 0xffff0000u);
  return fmaf(wh, hh, fmaf(wl, hl, acc));
}
#endif

// ---------------- threefry2x32 (JAX-exact) ----------------

__device__ __forceinline__ void tf_round(u32& x0, u32& x1, int r) {
  x0 += x1;
  x1 = (x1 << r) | (x1 >> (32 - r));
  x1 ^= x0;
}
__device__ void threefry(u32 k0, u32 k1, u32 c0, u32 c1, u32& o0, u32& o1) {
  u32 k2 = k0 ^ k1 ^ 0x1BD11BDAu;
  u32 x0 = c0 + k0, x1 = c1 + k1;
  tf_round(x0, x1, 13); tf_round(x0, x1, 15); tf_round(x0, x1, 26); tf_round(x0, x1, 6);
  x0 += k1; x1 += k2 + 1u;
  tf_round(x0, x1, 17); tf_round(x0, x1, 29); tf_round(x0, x1, 16); tf_round(x0, x1, 24);
  x0 += k2; x1 += k0 + 2u;
  tf_round(x0, x1, 13); tf_round(x0, x1, 15); tf_round(x0, x1, 26); tf_round(x0, x1, 6);
  x0 += k0; x1 += k1 + 3u;
  tf_round(x0, x1, 17); tf_round(x0, x1, 29); tf_round(x0, x1, 16); tf_round(x0, x1, 24);
  x0 += k1; x1 += k2 + 4u;
  tf_round(x0, x1, 13); tf_round(x0, x1, 15); tf_round(x0, x1, 26); tf_round(x0, x1, 6);
  x0 += k2; x1 += k0 + 5u;
  o0 = x0; o1 = x1;
}

// JAX >= 0.4.36 default: jax_threefry_partitionable = True.
// Flip to 0 for the legacy (original) threefry counter scheme.
#define JAX_PARTITIONABLE 1

// masks layout: [layer(2)][type(3: out,h,c)][b*256+h (16384)]
__global__ void masks_kernel(float* __restrict__ masks) {
  int gid = blockIdx.x * 256 + threadIdx.x;
  if (gid >= 2 * 3 * 16384) return;
  int l = gid / 49152;
  int rem = gid - l * 49152;
  int typ = rem / 16384;
  int i = rem - typ * 16384;
  u32 bits;
#if JAX_PARTITIONABLE
  u32 lk0, lk1, mk0, mk1, y0, y1;
  threefry(0u, 42u, 0u, (u32)l, lk0, lk1);      // split(MASK_KEY,2)[l]
  threefry(lk0, lk1, 0u, (u32)typ, mk0, mk1);   // split(layer_key,3)[typ]
  threefry(mk0, mk1, 0u, (u32)i, y0, y1);       // random_bits, counter = linear idx
  bits = y0 ^ y1;
#else
  u32 a0, a1, b0, b1;
  threefry(0u, 42u, 0u, 2u, a0, a1);            // split2 eval: tf(key;0,2)
  threefry(0u, 42u, 1u, 3u, b0, b1);            // tf(key;1,3)
  u32 lk0 = (l == 0) ? a0 : a1;
  u32 lk1 = (l == 0) ? b0 : b1;
  u32 e00, e01, e10, e11, e20, e21;
  threefry(lk0, lk1, 0u, 3u, e00, e01);
  threefry(lk0, lk1, 1u, 4u, e10, e11);
  threefry(lk0, lk1, 2u, 5u, e20, e21);
  u32 mk0 = (typ == 0) ? e00 : (typ == 1) ? e20 : e11;
  u32 mk1 = (typ == 0) ? e10 : (typ == 1) ? e01 : e21;
  u32 p = (i < 8192) ? (u32)i : (u32)(i - 8192);
  u32 y0, y1;
  threefry(mk0, mk1, p, p + 8192u, y0, y1);
  bits = (i < 8192) ? y0 : y1;
#endif
  float u = __uint_as_float((bits >> 9) | 0x3f800000u) - 1.0f;
  masks[gid] = (u < 0.75f) ? (1.0f / 0.75f) : 0.0f;
}

// ---------------- prep kernels ----------------

__global__ void conv_bf16(const float* __restrict__ src, u16* __restrict__ dst, int n) {
  int gid = blockIdx.x * 256 + threadIdx.x;
  if (gid < n) dst[gid] = f2bf(src[gid]);
}

// W_hh [1024][256] f32 -> Wp [128 pairs][1024 rows] packed bf16x2 (pair p = k 2p,2p+1)
// also Ws [1024 rows][16] = pairs 112..127 contiguous per row (streamed tail)
__global__ void pack_whh(const float* __restrict__ W, u32* __restrict__ Wp, u32* __restrict__ Ws) {
  int gid = blockIdx.x * 256 + threadIdx.x;  // 131072
  int p = gid >> 10;
  int row = gid & 1023;
  u32 lo = f2bf(W[row * 256 + 2 * p]);
  u32 hi = f2bf(W[row * 256 + 2 * p + 1]);
  u32 v = lo | (hi << 16);
  Wp[p * 1024 + row] = v;
  if (p >= 112) Ws[row * 16 + (p - 112)] = v;
}

__global__ void add_bias(const float* __restrict__ a, const float* __restrict__ b,
                         float* __restrict__ o, int n) {
  int gid = blockIdx.x * 256 + threadIdx.x;
  if (gid < n) o[gid] = a[gid] + b[gid];
}

// ---------------- input-projection GEMM (bf16 MFMA) ----------------
// C[m][n] = sum_k A[m][k] * Bw[n][k];  A [32768][256] bf16, Bw [1024][256] bf16
// output scattered into xg[t][b][n] with m = b*512 + t
__global__ __launch_bounds__(256) void gemm_xg(const u16* __restrict__ A,
                                               const u16* __restrict__ Bw,
                                               float* __restrict__ xg) {
  __shared__ uint4 Als[2048];  // [kb 0..31][m 0..63], 16B units (8 bf16 along k)
  __shared__ uint4 Bls[2048];
  int tid = threadIdx.x;
  int m0 = blockIdx.x * 64;
  int n0 = blockIdx.y * 64;
  {
    int row = tid >> 2, kseg = tid & 3;
    const uint4* Ag = (const uint4*)(A + (size_t)(m0 + row) * 256);
    const uint4* Bg = (const uint4*)(Bw + (size_t)(n0 + row) * 256);
#pragma unroll
    for (int uu = 0; uu < 8; ++uu) {
      int kb = kseg * 8 + uu;
      Als[kb * 64 + row] = Ag[kb];
      Bls[kb * 64 + row] = Bg[kb];
    }
  }
  __syncthreads();
  int w = tid >> 6, l = tid & 63;
  int wm = (w >> 1) * 32, wn = (w & 1) * 32;
  int lm = l & 15, q = l >> 4;
  f32x4 acc00 = {0.f, 0.f, 0.f, 0.f}, acc01 = acc00, acc10 = acc00, acc11 = acc00;
#pragma unroll
  for (int ks = 0; ks < 8; ++ks) {
    int kb = ks * 4 + q;
    short8 a0 = __builtin_bit_cast(short8, Als[kb * 64 + wm + lm]);
    short8 a1 = __builtin_bit_cast(short8, Als[kb * 64 + wm + 16 + lm]);
    short8 b0 = __builtin_bit_cast(short8, Bls[kb * 64 + wn + lm]);
    short8 b1 = __builtin_bit_cast(short8, Bls[kb * 64 + wn + 16 + lm]);
    acc00 = __builtin_amdgcn_mfma_f32_16x16x32_bf16(a0, b0, acc00, 0, 0, 0);
    acc01 = __builtin_amdgcn_mfma_f32_16x16x32_bf16(a0, b1, acc01, 0, 0, 0);
    acc10 = __builtin_amdgcn_mfma_f32_16x16x32_bf16(a1, b0, acc10, 0, 0, 0);
    acc11 = __builtin_amdgcn_mfma_f32_16x16x32_bf16(a1, b1, acc11, 0, 0, 0);
  }
#pragma unroll
  for (int fm = 0; fm < 2; ++fm)
#pragma unroll
    for (int fn = 0; fn < 2; ++fn) {
      f32x4 acc = (fm == 0) ? ((fn == 0) ? acc00 : acc01) : ((fn == 0) ? acc10 : acc11);
#pragma unroll
      for (int r = 0; r < 4; ++r) {
        int m = m0 + wm + fm * 16 + q * 4 + r;  // C/D row = quad*4 + reg
        int n = n0 + wn + fn * 16 + lm;         // C/D col = lane&15
        int bb = m >> 9, tt = m & 511;
        xg[(size_t)tt * 65536 + (size_t)bb * 1024 + n] = acc[r];
      }
    }
}

// ---------------- persistent recurrence ----------------
// One WG per batch element. W_hh bf16: pairs 0..97 in VGPRs, 98..111 in LDS,
// 112..127 streamed (L2-hot, 64B/row). h broadcast via LDS bf16 pairs.
#define REG_P 98
#define LDS_P 14

__global__ __launch_bounds__(512) void lstm_rec(
    const u32* __restrict__ Wp,      // [128][1024]
    const uint4* __restrict__ Ws,    // [1024][4] (16 u32 per row = pairs 112..127)
    const float* __restrict__ xg,    // [512][64][1024]
    const float* __restrict__ bias,  // [1024] (b_ih + b_hh)
    const float* __restrict__ masks, // [3][16384] this layer (out,h,c)
    float* __restrict__ outF,        // layer2: d_out [64][512][256], else null
    u16* __restrict__ outB)          // layer1: bf16 out for next GEMM, else null
{
  __shared__ u32 Wl[LDS_P * 1024];
  __shared__ float gates[1024];
  __shared__ alignas(16) u16 hbf[256];

  const int tid = threadIdx.x;
  const int b = blockIdx.x;
  const int r0 = tid, r1 = tid + 512;

  u32 wreg[2 * REG_P];
#pragma unroll
  for (int p = 0; p < REG_P; ++p) wreg[p] = Wp[p * 1024 + r0];
#pragma unroll
  for (int p = 0; p < REG_P; ++p) wreg[REG_P + p] = Wp[p * 1024 + r1];

#pragma unroll
  for (int s = 0; s < LDS_P; ++s) {
    Wl[s * 1024 + r0] = Wp[(REG_P + s) * 1024 + r0];
    Wl[s * 1024 + r1] = Wp[(REG_P + s) * 1024 + r1];
  }
  if (tid < 256) hbf[tid] = 0;

  const float bias0 = bias[r0];
  const float bias1 = bias[r1];
  float c = 0.f, m_out = 0.f, m_h = 0.f, m_c = 0.f;
  if (tid < 256) {
    m_out = masks[0 * 16384 + b * 256 + tid];
    m_h   = masks[1 * 16384 + b * 256 + tid];
    m_c   = masks[2 * 16384 + b * 256 + tid];
  }
  const uint4* Wsr0 = Ws + (size_t)r0 * 4;
  const uint4* Wsr1 = Ws + (size_t)r1 * 4;
  const float* xgb = xg + b * 1024;
  float* outFb = outF ? outF + (size_t)b * 512 * 256 : (float*)0;
  u16* outBb = outB ? outB + (size_t)b * 512 * 256 : (u16*)0;

  __syncthreads();

  for (int t = 0; t < 512; ++t) {
    float xg0 = xgb[(size_t)t * 65536 + r0];
    float xg1 = xgb[(size_t)t * 65536 + r1];
    float acc0 = bias0, acc1 = bias1;
    const uint4* h4 = (const uint4*)hbf;
    // streamed tail: pairs 112..127, consumed immediately (L2-hot)
#pragma unroll
    for (int s4 = 0; s4 < 4; ++s4) {
      uint4 v0 = Wsr0[s4];
      uint4 v1 = Wsr1[s4];
      uint4 hp = h4[28 + s4];
      acc0 = dot2bf(v0.x, hp.x, acc0); acc1 = dot2bf(v1.x, hp.x, acc1);
      acc0 = dot2bf(v0.y, hp.y, acc0); acc1 = dot2bf(v1.y, hp.y, acc1);
      acc0 = dot2bf(v0.z, hp.z, acc0); acc1 = dot2bf(v1.z, hp.z, acc1);
      acc0 = dot2bf(v0.w, hp.w, acc0); acc1 = dot2bf(v1.w, hp.w, acc1);
    }
    // register + LDS W: pairs 0..111
#pragma unroll
    for (int qq = 0; qq < 28; ++qq) {
      uint4 hp = h4[qq];
      u32 hh[4] = {hp.x, hp.y, hp.z, hp.w};
#pragma unroll
      for (int e = 0; e < 4; ++e) {
        const int p = qq * 4 + e;
        u32 w0, w1;
        if (p < REG_P) {
          w0 = wreg[p];
          w1 = wreg[REG_P + p];
        } else {
          w0 = Wl[(p - REG_P) * 1024 + r0];
          w1 = Wl[(p - REG_P) * 1024 + r1];
        }
        acc0 = dot2bf(w0, hh[e], acc0);
        acc1 = dot2bf(w1, hh[e], acc1);
      }
    }
    acc0 += xg0;
    acc1 += xg1;
    gates[r0] = acc0;
    gates[r1] = acc1;
    __syncthreads();
    if (tid < 256) {
      float gi = gates[tid];
      float gf = gates[tid + 256];
      float gg = gates[tid + 512];
      float go = gates[tid + 768];
      float fi = sigmf_(gi), ff = sigmf_(gf), fo = sigmf_(go);
      float tg = tanhf_(gg);
      c = ff * c + fi * tg;
      float hn = fo * tanhf_(c);
      float ov = hn * m_out;
      if (outFb) outFb[t * 256 + tid] = ov;
      if (outBb) outBb[t * 256 + tid] = f2bf(ov);
      hbf[tid] = f2bf(hn * m_h);  // variational h-mask applied to carry
      c *= m_c;                   // c-mask applied to carry
    }
    __syncthreads();
  }
}

// ---------------- launch ----------------

extern "C" void kernel_launch(void* const* d_in, const int* in_sizes, int n_in,
                              void* d_out, int out_size, void* d_ws, size_t ws_size,
                              hipStream_t stream) {
  const float* x    = (const float*)d_in[0];
  const float* Wih0 = (const float*)d_in[1];
  const float* Whh0 = (const float*)d_in[2];
  const float* bih0 = (const float*)d_in[3];
  const float* bhh0 = (const float*)d_in[4];
  const float* Wih1 = (const float*)d_in[5];
  const float* Whh1 = (const float*)d_in[6];
  const float* bih1 = (const float*)d_in[7];
  const float* bhh1 = (const float*)d_in[8];
  float* out = (float*)d_out;

  char* w = (char*)d_ws;
  float* masks = (float*)(w + 0);             // 393216 B
  float* biasb = (float*)(w + 393216);        // 8192 B
  u32* Wp0     = (u32*)(w + 401408);          // 524288 B
  u32* Wp1     = (u32*)(w + 925696);          // 524288 B
  u32* Ws0     = (u32*)(w + 1449984);         // 65536 B
  u32* Ws1     = (u32*)(w + 1515520);         // 65536 B
  u16* Wih0b   = (u16*)(w + 1581056);         // 524288 B
  u16* Wih1b   = (u16*)(w + 2105344);         // 524288 B
  u16* xb      = (u16*)(w + 2629632);         // 16777216 B
  u16* o1b     = (u16*)(w + 19406848);        // 16777216 B
  float* xg    = (float*)(w + 36184064);      // 134217728 B  (total ~170.4 MB)

  hipLaunchKernelGGL(masks_kernel, dim3(384), dim3(256), 0, stream, masks);
  hipLaunchKernelGGL(conv_bf16, dim3(32768), dim3(256), 0, stream, x, xb, 8388608);
  hipLaunchKernelGGL(conv_bf16, dim3(1024), dim3(256), 0, stream, Wih0, Wih0b, 262144);
  hipLaunchKernelGGL(conv_bf16, dim3(1024), dim3(256), 0, stream, Wih1, Wih1b, 262144);
  hipLaunchKernelGGL(pack_whh, dim3(512), dim3(256), 0, stream, Whh0, Wp0, Ws0);
  hipLaunchKernelGGL(pack_whh, dim3(512), dim3(256), 0, stream, Whh1, Wp1, Ws1);
  hipLaunchKernelGGL(add_bias, dim3(4), dim3(256), 0, stream, bih0, bhh0, biasb, 1024);
  hipLaunchKernelGGL(add_bias, dim3(4), dim3(256), 0, stream, bih1, bhh1, biasb + 1024, 1024);

  // layer 1
  hipLaunchKernelGGL(gemm_xg, dim3(512, 16), dim3(256), 0, stream, xb, Wih0b, xg);
  hipLaunchKernelGGL(lstm_rec, dim3(64), dim3(512), 0, stream, Wp0, (const uint4*)Ws0, xg,
                     biasb, masks, (float*)nullptr, o1b);
  // layer 2
  hipLaunchKernelGGL(gemm_xg, dim3(512, 16), dim3(256), 0, stream, o1b, Wih1b, xg);
  hipLaunchKernelGGL(lstm_rec, dim3(64), dim3(512), 0, stream, Wp1, (const uint4*)Ws1, xg,
                     biasb + 1024, masks + 49152, out, (u16*)nullptr);
}